// Round 11
// baseline (724.040 us; speedup 1.0000x reference)
//
#include <hip/hip_runtime.h>
#include <hip/hip_bf16.h>

typedef float f32x4 __attribute__((ext_vector_type(4)));
typedef int   i32x4 __attribute__((ext_vector_type(4)));
typedef __bf16 bf16x8 __attribute__((ext_vector_type(8)));
typedef unsigned short u16;
typedef unsigned short u16x4 __attribute__((ext_vector_type(4)));
typedef unsigned short u16x8 __attribute__((ext_vector_type(8)));

#define BM 128
#define BN 128
#define BK 32
#define NT 256
#define MAXE 32

__device__ __forceinline__ u16 f2bf(float f) {
  __bf16 h = (__bf16)f;
  return __builtin_bit_cast(u16, h);
}

__global__ __launch_bounds__(256)
void cvt_bf16(const float* __restrict__ in, u16* __restrict__ out, int n8) {
  int i = blockIdx.x * 256 + threadIdx.x;
  if (i < n8) {
    f32x4 a = *(const f32x4*)(in + (long long)i * 8);
    f32x4 b = *(const f32x4*)(in + (long long)i * 8 + 4);
    u16x8 r = { f2bf(a[0]), f2bf(a[1]), f2bf(a[2]), f2bf(a[3]),
                f2bf(b[0]), f2bf(b[1]), f2bf(b[2]), f2bf(b[3]) };
    *(u16x8*)(out + (long long)i * 8) = r;
  }
}

__device__ __forceinline__ int expert_lookup(const int* counts, int E, int bm,
                                             int mt_in, int& row0, int& cnt, int& mt) {
  int cs[MAXE];
#pragma unroll
  for (int j = 0; j < MAXE / 4; ++j) {
    if (j * 4 + 3 < E) *(i32x4*)&cs[j * 4] = *(const i32x4*)(counts + j * 4);
    else {
#pragma unroll
      for (int q = 0; q < 4; ++q) cs[j*4+q] = (j*4+q < E) ? counts[j*4+q] : 0;
    }
  }
  int e = -1; row0 = 0; cnt = 0; mt = mt_in;
#pragma unroll
  for (int i = 0; i < MAXE; ++i) {
    if (i < E && e < 0) {
      int ntl = (cs[i] + bm - 1) / bm;
      if (mt < ntl) { e = i; cnt = cs[i]; }
      else { mt -= ntl; row0 += cs[i]; }
    }
  }
  return e;
}

// ================= shared GEMM1-shaped body (r3 template) =================
// MODE 0: real (fp32 B, full behavior)
// MODE 1: B read as-if-bf16 (same #loads, half bytes, no cvt)  [byte-volume probe]
// MODE 2: B k-offset alternates 2 slices -> L2-hot B           [latency probe]
// MODE 3: A k-offset alternates 2 slices -> L2-hot A           [control]
// MASK:   write to (row & 2047) rows of Out (scratch mode; d_out overwritten by G2)
template<int MODE, bool MASK>
__device__ __forceinline__ void gbody(const u16* __restrict__ Ain,
                                      const float* __restrict__ Bw,
                                      const float* __restrict__ bias,
                                      u16* __restrict__ Out,
                                      const int* __restrict__ counts,
                                      int E, int T, int N, int K)
{
  int row0, cnt, mt;
  int e = expert_lookup(counts, E, BM, blockIdx.y, row0, cnt, mt);
  if (e < 0) return;
  int valid = cnt - mt * BM; if (valid > BM) valid = BM;
  row0 += mt * BM;
  const int n0 = blockIdx.x * BN;

  const float* Be = Bw + (long long)e * N * K;
  const u16*   Be16 = (const u16*)Bw + (long long)e * N * K;  // MODE1 reinterpret
  const float* be = bias + (long long)e * N;

  __shared__ u16 As[2][BM][BK];
  __shared__ u16 Bs[2][BN][BK];

  const int t = threadIdx.x;
  const int lane = t & 63;
  const int w = t >> 6, wr = w >> 1, wc = w & 1;
  const int NKT = K / BK;

  long long offA[2];
  int aRow[2], aCol[2];
#pragma unroll
  for (int i = 0; i < 2; ++i) {
    int c = i * NT + t;
    aRow[i] = c >> 2; aCol[i] = (c & 3) << 3;
    int gr = row0 + aRow[i]; if (gr > T - 1) gr = T - 1;
    offA[i] = (long long)gr * K + aCol[i];
  }
  long long offB[4]; int bRow[4], bCol[4];
#pragma unroll
  for (int i = 0; i < 4; ++i) {
    int c = i * NT + t;
    bRow[i] = c >> 3; bCol[i] = (c & 7) << 2;
    offB[i] = (long long)(n0 + bRow[i]) * K + bCol[i];
  }
  // bf16-B (MODE1): same mapping as A (2 shots of u16x8)
  long long offB16[2]; int b16Row[2], b16Col[2];
#pragma unroll
  for (int i = 0; i < 2; ++i) {
    int c = i * NT + t;
    b16Row[i] = c >> 2; b16Col[i] = (c & 3) << 3;
    offB16[i] = (long long)(n0 + b16Row[i]) * K + b16Col[i];
  }

  f32x4 acc[4][4];
#pragma unroll
  for (int i = 0; i < 4; ++i)
#pragma unroll
    for (int j = 0; j < 4; ++j) acc[i][j] = (f32x4){0.f, 0.f, 0.f, 0.f};

  u16x8 rAu[2]; float rB[16]; u16x8 rBu[2];

  auto load_g = [&](int kt) {
    const int k0a = (MODE == 3) ? (kt & 1) * BK : kt * BK;
    const int k0b = (MODE == 2) ? (kt & 1) * BK : kt * BK;
#pragma unroll
    for (int i = 0; i < 2; ++i)
      rAu[i] = *(const u16x8*)(Ain + offA[i] + k0a);
    if constexpr (MODE == 1) {
#pragma unroll
      for (int i = 0; i < 2; ++i)
        rBu[i] = *(const u16x8*)(Be16 + offB16[i] + k0b);
    } else {
#pragma unroll
      for (int i = 0; i < 4; ++i) {
        f32x4 v = *(const f32x4*)(Be + offB[i] + k0b);
        rB[i*4+0] = v[0]; rB[i*4+1] = v[1]; rB[i*4+2] = v[2]; rB[i*4+3] = v[3];
      }
    }
  };

  auto store_tile = [&](int buf) {
#pragma unroll
    for (int i = 0; i < 2; ++i) {
      int row = aRow[i], col = aCol[i];
      int kg2 = (col >> 3) ^ ((row >> 1) & 3);
      *(u16x8*)&As[buf][row][kg2 * 8] = rAu[i];
    }
    if constexpr (MODE == 1) {
#pragma unroll
      for (int i = 0; i < 2; ++i) {
        int row = b16Row[i], col = b16Col[i];
        int kg2 = (col >> 3) ^ ((row >> 1) & 3);
        *(u16x8*)&Bs[buf][row][kg2 * 8] = rBu[i];
      }
    } else {
#pragma unroll
      for (int i = 0; i < 4; ++i) {
        int row = bRow[i], col = bCol[i];
        int kg2 = (col >> 3) ^ ((row >> 1) & 3);
        int off = kg2 * 8 + ((col >> 2) & 1) * 4;
        u16x4 pk = { f2bf(rB[i*4+0]), f2bf(rB[i*4+1]), f2bf(rB[i*4+2]), f2bf(rB[i*4+3]) };
        *(u16x4*)&Bs[buf][row][off] = pk;
      }
    }
  };

  load_g(0);
  store_tile(0);
  load_g(1);
  __syncthreads();

  const int rl = lane & 15;
  const int kgf = (lane >> 4) ^ ((rl >> 1) & 3);

  for (int kt = 0; kt < NKT; ++kt) {
    const int cur = kt & 1;

    bf16x8 af[4], bfr[4];
#pragma unroll
    for (int mf = 0; mf < 4; ++mf)
      af[mf] = __builtin_bit_cast(bf16x8, *(const u16x8*)&As[cur][wr*64 + mf*16 + rl][kgf*8]);
#pragma unroll
    for (int nf = 0; nf < 4; ++nf)
      bfr[nf] = __builtin_bit_cast(bf16x8, *(const u16x8*)&Bs[cur][wc*64 + nf*16 + rl][kgf*8]);

    if (kt + 1 < NKT) store_tile(cur ^ 1);
    if (kt + 2 < NKT) load_g(kt + 2);

#pragma unroll
    for (int mf = 0; mf < 4; ++mf)
#pragma unroll
      for (int nf = 0; nf < 4; ++nf)
        acc[mf][nf] = __builtin_amdgcn_mfma_f32_16x16x32_bf16(af[mf], bfr[nf], acc[mf][nf], 0, 0, 0);

    if (kt + 1 < NKT) __syncthreads();
  }

  const int cl = lane & 15, rg = lane >> 4;
#pragma unroll
  for (int mf = 0; mf < 4; ++mf) {
#pragma unroll
    for (int nf = 0; nf < 4; ++nf) {
      int gcol = n0 + wc*64 + nf*16 + cl;
      float bv = be[gcol];
#pragma unroll
      for (int r = 0; r < 4; ++r) {
        int lrow = wr*64 + mf*16 + rg*4 + r;
        if (lrow < valid) {
          float v = acc[mf][nf][r] + bv;
          v = 0.5f * v * (1.0f + erff(v * 0.70710678118654752f));
          long long rr = MASK ? (long long)((row0 + lrow) & 2047) : (long long)(row0 + lrow);
          Out[rr * N + gcol] = f2bf(v);
        }
      }
    }
  }
}

__global__ __launch_bounds__(256)
void ffn_gemm1(const u16* A, const float* B, const float* bi, u16* O,
               const int* c, int E, int T, int N, int K) { gbody<0,false>(A,B,bi,O,c,E,T,N,K); }
__global__ __launch_bounds__(256)
void pr_bw16(const u16* A, const float* B, const float* bi, u16* O,
             const int* c, int E, int T, int N, int K) { gbody<1,true>(A,B,bi,O,c,E,T,N,K); }
__global__ __launch_bounds__(256)
void pr_wB(const u16* A, const float* B, const float* bi, u16* O,
           const int* c, int E, int T, int N, int K) { gbody<2,true>(A,B,bi,O,c,E,T,N,K); }
__global__ __launch_bounds__(256)
void pr_wA(const u16* A, const float* B, const float* bi, u16* O,
           const int* c, int E, int T, int N, int K) { gbody<3,true>(A,B,bi,O,c,E,T,N,K); }

// ================= GEMM2: r3 reg-staged template (proven ~859 TF) =================
template<bool DO_GELU, bool OUT_BF16>
__global__ __launch_bounds__(NT)
void ffn_gemm(const u16* __restrict__ Ain, const float* __restrict__ Bw,
              const float* __restrict__ bias, void* __restrict__ Out,
              const int* __restrict__ counts, int E, int T, int N, int K)
{
  int row0, cnt, mt;
  int e = expert_lookup(counts, E, BM, blockIdx.y, row0, cnt, mt);
  if (e < 0) return;
  int valid = cnt - mt * BM; if (valid > BM) valid = BM;
  row0 += mt * BM;
  const int n0 = blockIdx.x * BN;

  const float* Be = Bw + (long long)e * N * K;
  const float* be = bias + (long long)e * N;

  __shared__ u16 As[2][BM][BK];
  __shared__ u16 Bs[2][BN][BK];

  const int t = threadIdx.x;
  const int lane = t & 63;
  const int w = t >> 6, wr = w >> 1, wc = w & 1;
  const int NKT = K / BK;

  long long offA[2];
#pragma unroll
  for (int i = 0; i < 2; ++i) {
    int c = i * NT + t;
    int row = c >> 2, col = (c & 3) << 3;
    int gr = row0 + row; if (gr > T - 1) gr = T - 1;
    offA[i] = (long long)gr * K + col;
  }
  long long offB[4];
#pragma unroll
  for (int i = 0; i < 4; ++i) {
    int c = i * NT + t;
    offB[i] = (long long)(n0 + (c >> 3)) * K + ((c & 7) << 2);
  }

  f32x4 acc[4][4];
#pragma unroll
  for (int i = 0; i < 4; ++i)
#pragma unroll
    for (int j = 0; j < 4; ++j) acc[i][j] = (f32x4){0.f, 0.f, 0.f, 0.f};

  u16x8 rAu[2]; float rB[16];

  auto load_g = [&](int kt) {
    const int k0 = kt * BK;
#pragma unroll
    for (int i = 0; i < 2; ++i)
      rAu[i] = *(const u16x8*)(Ain + offA[i] + k0);
#pragma unroll
    for (int i = 0; i < 4; ++i) {
      f32x4 v = *(const f32x4*)(Be + offB[i] + k0);
      rB[i*4+0] = v[0]; rB[i*4+1] = v[1]; rB[i*4+2] = v[2]; rB[i*4+3] = v[3];
    }
  };

  auto store_tile = [&](int buf) {
#pragma unroll
    for (int i = 0; i < 2; ++i) {
      int c = i * NT + t;
      int row = c >> 2, col = (c & 3) << 3;
      int kg2 = (col >> 3) ^ ((row >> 1) & 3);
      *(u16x8*)&As[buf][row][kg2 * 8] = rAu[i];
    }
#pragma unroll
    for (int i = 0; i < 4; ++i) {
      int c = i * NT + t;
      int row = c >> 3, col = (c & 7) << 2;
      int kg2 = (col >> 3) ^ ((row >> 1) & 3);
      int off = kg2 * 8 + ((col >> 2) & 1) * 4;
      u16x4 pk = { f2bf(rB[i*4+0]), f2bf(rB[i*4+1]), f2bf(rB[i*4+2]), f2bf(rB[i*4+3]) };
      *(u16x4*)&Bs[buf][row][off] = pk;
    }
  };

  load_g(0);
  store_tile(0);
  load_g(1);
  __syncthreads();

  const int rl = lane & 15;
  const int kgf = (lane >> 4) ^ ((rl >> 1) & 3);

  for (int kt = 0; kt < NKT; ++kt) {
    const int cur = kt & 1;

    bf16x8 af[4], bfr[4];
#pragma unroll
    for (int mf = 0; mf < 4; ++mf)
      af[mf] = __builtin_bit_cast(bf16x8, *(const u16x8*)&As[cur][wr*64 + mf*16 + rl][kgf*8]);
#pragma unroll
    for (int nf = 0; nf < 4; ++nf)
      bfr[nf] = __builtin_bit_cast(bf16x8, *(const u16x8*)&Bs[cur][wc*64 + nf*16 + rl][kgf*8]);

    if (kt + 1 < NKT) store_tile(cur ^ 1);
    if (kt + 2 < NKT) load_g(kt + 2);

#pragma unroll
    for (int mf = 0; mf < 4; ++mf)
#pragma unroll
      for (int nf = 0; nf < 4; ++nf)
        acc[mf][nf] = __builtin_amdgcn_mfma_f32_16x16x32_bf16(af[mf], bfr[nf], acc[mf][nf], 0, 0, 0);

    if (kt + 1 < NKT) __syncthreads();
  }

  const int cl = lane & 15, rg = lane >> 4;
#pragma unroll
  for (int mf = 0; mf < 4; ++mf) {
#pragma unroll
    for (int nf = 0; nf < 4; ++nf) {
      int gcol = n0 + wc*64 + nf*16 + cl;
      float bv = be[gcol];
#pragma unroll
      for (int r = 0; r < 4; ++r) {
        int lrow = wr*64 + mf*16 + rg*4 + r;
        if (lrow < valid) {
          float v = acc[mf][nf][r] + bv;
          if constexpr (DO_GELU)
            v = 0.5f * v * (1.0f + erff(v * 0.70710678118654752f));
          long long idx = (long long)(row0 + lrow) * N + gcol;
          if constexpr (OUT_BF16) ((u16*)Out)[idx] = f2bf(v);
          else                    ((float*)Out)[idx] = v;
        }
      }
    }
  }
}

extern "C" void kernel_launch(void* const* d_in, const int* in_sizes, int n_in,
                              void* d_out, int out_size, void* d_ws, size_t ws_size,
                              hipStream_t stream) {
  const float* inp = (const float*)d_in[0];
  const float* w1  = (const float*)d_in[1];
  const float* b1  = (const float*)d_in[2];
  const float* w2  = (const float*)d_in[3];
  const float* b2  = (const float*)d_in[4];
  const int* cnts  = (const int*)d_in[5];

  const int E = in_sizes[5];
  const int H = in_sizes[2] / E;       // 4096
  const int D = in_sizes[4] / E;       // 1024
  const int T = in_sizes[0] / D;       // 8192

  u16* hbuf = (u16*)d_ws;                                  // T*H bf16 (64 MB)
  u16* ibuf = (u16*)((char*)d_ws + (size_t)T * H * 2);     // T*D bf16 (16 MB)

  // 0) inp -> bf16
  const int n8 = (T * D) / 8;
  cvt_bf16<<<dim3((n8 + 255) / 256), dim3(256), 0, stream>>>(inp, ibuf, n8);

  const int tiles = T / BM + E;

  // 1) REAL G1 on cold w1 (baseline-comparable), writes correct hbuf
  ffn_gemm1<<<dim3(H / BN, tiles), dim3(NT), 0, stream>>>(
      ibuf, w1, b1, hbuf, cnts, E, T, H, D);

  // --- ABLATION PROBES (scratch = d_out; G2 overwrites it below) ---
  // P2: B as bf16 (byte-volume).  null ~125us; bytes-theory ~60-70
  pr_bw16<<<dim3(H / BN, 32), dim3(NT), 0, stream>>>(
      ibuf, w1, b1, (u16*)d_out, cnts, E, T, H, D);
  // P3: L2-warm B (latency).     null ~185us; latency-theory ~60-90
  pr_wB<<<dim3(H / BN, 48), dim3(NT), 0, stream>>>(
      ibuf, w1, b1, (u16*)d_out, cnts, E, T, H, D);
  // P4: L2-warm A (control).     expect ~62us regardless
  pr_wA<<<dim3(H / BN, 16), dim3(NT), 0, stream>>>(
      ibuf, w1, b1, (u16*)d_out, cnts, E, T, H, D);

  // 2) REAL G2 — overwrites every element of d_out (correct final output)
  ffn_gemm<false, false><<<dim3(D / BN, tiles), dim3(NT), 0, stream>>>(
      hbuf, w2, b2, d_out, cnts, E, T, D, H);
}

// Round 12
// 345.144 us; speedup vs baseline: 2.0978x; 2.0978x over previous
//
#include <hip/hip_runtime.h>
#include <hip/hip_bf16.h>

typedef float f32x4 __attribute__((ext_vector_type(4)));
typedef int   i32x4 __attribute__((ext_vector_type(4)));
typedef __bf16 bf16x8 __attribute__((ext_vector_type(8)));
typedef unsigned short u16;
typedef unsigned short u16x4 __attribute__((ext_vector_type(4)));
typedef unsigned short u16x8 __attribute__((ext_vector_type(8)));

#define BM 128
#define BN 128
#define BK 32
#define NT 256
#define MAXE 32

__device__ __forceinline__ u16 f2bf(float f) {
  __bf16 h = (__bf16)f;
  return __builtin_bit_cast(u16, h);
}
__device__ __forceinline__ float bf2f(u16 u) {
  unsigned v = (unsigned)u << 16;
  return __builtin_bit_cast(float, v);
}

// inp fp32 -> bf16 pre-pass
__global__ __launch_bounds__(256)
void cvt_bf16(const float* __restrict__ in, u16* __restrict__ out, int n8) {
  int i = blockIdx.x * 256 + threadIdx.x;
  if (i < n8) {
    f32x4 a = *(const f32x4*)(in + (long long)i * 8);
    f32x4 b = *(const f32x4*)(in + (long long)i * 8 + 4);
    u16x8 r = { f2bf(a[0]), f2bf(a[1]), f2bf(a[2]), f2bf(a[3]),
                f2bf(b[0]), f2bf(b[1]), f2bf(b[2]), f2bf(b[3]) };
    *(u16x8*)(out + (long long)i * 8) = r;
  }
}

// r11 finding: the erff-gelu epilogue inside the GEMM costs ~21us per 128^2
// block (~50k cyc; 64x unrolled erff = ~20KB code -> I-cache thrash) and was
// ~70% of G1's runtime, invariant under tiling. Moved here: one streaming
// in-place pass over hbuf (128 MB traffic), erff confined to a small kernel.
__global__ __launch_bounds__(256)
void gelu_pass(u16* __restrict__ h, int n8) {
  int i = blockIdx.x * 256 + threadIdx.x;
  if (i < n8) {
    u16x8 v = *(const u16x8*)(h + (long long)i * 8);
    u16x8 r;
#pragma unroll
    for (int j = 0; j < 8; ++j) {
      float x = bf2f(v[j]);
      x = 0.5f * x * (1.0f + erff(x * 0.70710678118654752f));
      r[j] = f2bf(x);
    }
    *(u16x8*)(h + (long long)i * 8) = r;
  }
}

__device__ __forceinline__ int expert_lookup(const int* counts, int E, int bm,
                                             int mt_in, int& row0, int& cnt, int& mt) {
  int cs[MAXE];
#pragma unroll
  for (int j = 0; j < MAXE / 4; ++j) {
    if (j * 4 + 3 < E) *(i32x4*)&cs[j * 4] = *(const i32x4*)(counts + j * 4);
    else {
#pragma unroll
      for (int q = 0; q < 4; ++q) cs[j*4+q] = (j*4+q < E) ? counts[j*4+q] : 0;
    }
  }
  int e = -1; row0 = 0; cnt = 0; mt = mt_in;
#pragma unroll
  for (int i = 0; i < MAXE; ++i) {
    if (i < E && e < 0) {
      int ntl = (cs[i] + bm - 1) / bm;
      if (mt < ntl) { e = i; cnt = cs[i]; }
      else { mt -= ntl; row0 += cs[i]; }
    }
  }
  return e;
}

// ======== grouped GEMM, r3 reg-staged template (proven; NO gelu inside) ========
// Out[m,n] = sum_k A[m,k]*B[e][n,k] + bias[e][n]
template<bool OUT_BF16>
__global__ __launch_bounds__(NT)
void ffn_gemm(const u16* __restrict__ Ain, const float* __restrict__ Bw,
              const float* __restrict__ bias, void* __restrict__ Out,
              const int* __restrict__ counts, int E, int T, int N, int K)
{
  int row0, cnt, mt;
  int e = expert_lookup(counts, E, BM, blockIdx.y, row0, cnt, mt);
  if (e < 0) return;
  int valid = cnt - mt * BM; if (valid > BM) valid = BM;
  row0 += mt * BM;
  const int n0 = blockIdx.x * BN;

  const float* Be = Bw + (long long)e * N * K;
  const float* be = bias + (long long)e * N;

  __shared__ u16 As[2][BM][BK];
  __shared__ u16 Bs[2][BN][BK];

  const int t = threadIdx.x;
  const int lane = t & 63;
  const int w = t >> 6, wr = w >> 1, wc = w & 1;   // 2x2 waves -> 64x64 each
  const int NKT = K / BK;

  long long offA[2];
#pragma unroll
  for (int i = 0; i < 2; ++i) {
    int c = i * NT + t;
    int row = c >> 2, col = (c & 3) << 3;
    int gr = row0 + row; if (gr > T - 1) gr = T - 1;
    offA[i] = (long long)gr * K + col;
  }
  long long offB[4];
#pragma unroll
  for (int i = 0; i < 4; ++i) {
    int c = i * NT + t;
    offB[i] = (long long)(n0 + (c >> 3)) * K + ((c & 7) << 2);
  }

  f32x4 acc[4][4];
#pragma unroll
  for (int i = 0; i < 4; ++i)
#pragma unroll
    for (int j = 0; j < 4; ++j) acc[i][j] = (f32x4){0.f, 0.f, 0.f, 0.f};

  u16x8 rAu[2]; float rB[16];

  auto load_g = [&](int kt) {
    const int k0 = kt * BK;
#pragma unroll
    for (int i = 0; i < 2; ++i)
      rAu[i] = *(const u16x8*)(Ain + offA[i] + k0);
#pragma unroll
    for (int i = 0; i < 4; ++i) {
      f32x4 v = *(const f32x4*)(Be + offB[i] + k0);
      rB[i*4+0] = v[0]; rB[i*4+1] = v[1]; rB[i*4+2] = v[2]; rB[i*4+3] = v[3];
    }
  };

  // XOR-swizzle on 16B granules (0 conflicts, r3-proven)
  auto store_tile = [&](int buf) {
#pragma unroll
    for (int i = 0; i < 2; ++i) {
      int c = i * NT + t;
      int row = c >> 2, col = (c & 3) << 3;
      int kg2 = (col >> 3) ^ ((row >> 1) & 3);
      *(u16x8*)&As[buf][row][kg2 * 8] = rAu[i];
    }
#pragma unroll
    for (int i = 0; i < 4; ++i) {
      int c = i * NT + t;
      int row = c >> 3, col = (c & 7) << 2;
      int kg2 = (col >> 3) ^ ((row >> 1) & 3);
      int off = kg2 * 8 + ((col >> 2) & 1) * 4;
      u16x4 pk = { f2bf(rB[i*4+0]), f2bf(rB[i*4+1]), f2bf(rB[i*4+2]), f2bf(rB[i*4+3]) };
      *(u16x4*)&Bs[buf][row][off] = pk;
    }
  };

  load_g(0);
  store_tile(0);
  load_g(1);
  __syncthreads();

  const int rl = lane & 15;
  const int kgf = (lane >> 4) ^ ((rl >> 1) & 3);

  for (int kt = 0; kt < NKT; ++kt) {
    const int cur = kt & 1;

    bf16x8 af[4], bfr[4];
#pragma unroll
    for (int mf = 0; mf < 4; ++mf)
      af[mf] = __builtin_bit_cast(bf16x8, *(const u16x8*)&As[cur][wr*64 + mf*16 + rl][kgf*8]);
#pragma unroll
    for (int nf = 0; nf < 4; ++nf)
      bfr[nf] = __builtin_bit_cast(bf16x8, *(const u16x8*)&Bs[cur][wc*64 + nf*16 + rl][kgf*8]);

    if (kt + 1 < NKT) store_tile(cur ^ 1);
    if (kt + 2 < NKT) load_g(kt + 2);

#pragma unroll
    for (int mf = 0; mf < 4; ++mf)
#pragma unroll
      for (int nf = 0; nf < 4; ++nf)
        acc[mf][nf] = __builtin_amdgcn_mfma_f32_16x16x32_bf16(af[mf], bfr[nf], acc[mf][nf], 0, 0, 0);

    if (kt + 1 < NKT) __syncthreads();
  }

  // epilogue: bias + store only (C/D col=lane&15, row=(lane>>4)*4+r [m89/m91])
  const int cl = lane & 15, rg = lane >> 4;
#pragma unroll
  for (int mf = 0; mf < 4; ++mf) {
#pragma unroll
    for (int nf = 0; nf < 4; ++nf) {
      int gcol = n0 + wc*64 + nf*16 + cl;
      float bv = be[gcol];
#pragma unroll
      for (int r = 0; r < 4; ++r) {
        int lrow = wr*64 + mf*16 + rg*4 + r;
        if (lrow < valid) {
          float v = acc[mf][nf][r] + bv;
          long long idx = (long long)(row0 + lrow) * N + gcol;
          if constexpr (OUT_BF16) ((u16*)Out)[idx] = f2bf(v);
          else                    ((float*)Out)[idx] = v;
        }
      }
    }
  }
}

extern "C" void kernel_launch(void* const* d_in, const int* in_sizes, int n_in,
                              void* d_out, int out_size, void* d_ws, size_t ws_size,
                              hipStream_t stream) {
  const float* inp = (const float*)d_in[0];
  const float* w1  = (const float*)d_in[1];
  const float* b1  = (const float*)d_in[2];
  const float* w2  = (const float*)d_in[3];
  const float* b2  = (const float*)d_in[4];
  const int* cnts  = (const int*)d_in[5];

  const int E = in_sizes[5];
  const int H = in_sizes[2] / E;       // 4096
  const int D = in_sizes[4] / E;       // 1024
  const int T = in_sizes[0] / D;       // 8192

  u16* hbuf = (u16*)d_ws;                                  // T*H bf16 (64 MB)
  u16* ibuf = (u16*)((char*)d_ws + (size_t)T * H * 2);     // T*D bf16 (16 MB)

  // 0) inp -> bf16
  const int n8i = (T * D) / 8;
  cvt_bf16<<<dim3((n8i + 255) / 256), dim3(256), 0, stream>>>(inp, ibuf, n8i);

  const int tiles = T / BM + E;

  // 1) h_pre = ibuf @ w1^T + b1   (NO gelu in epilogue)
  ffn_gemm<true><<<dim3(H / BN, tiles), dim3(NT), 0, stream>>>(
      ibuf, w1, b1, hbuf, cnts, E, T, H, D);

  // 1b) h = gelu(h_pre), streaming in-place
  const int n8h = (T * H) / 8;
  gelu_pass<<<dim3((n8h + 255) / 256), dim3(256), 0, stream>>>(hbuf, n8h);

  // 2) out = h @ w2^T + b2
  ffn_gemm<false><<<dim3(D / BN, tiles), dim3(NT), 0, stream>>>(
      hbuf, w2, b2, d_out, cnts, E, T, D, H);
}